// Round 14
// baseline (97.239 us; speedup 1.0000x reference)
//
#include <hip/hip_runtime.h>
#include <hip/hip_bf16.h>

#define B_  8
#define S_  2048
#define DIN 1024
#define DH  64

typedef __bf16 bf16;
typedef __attribute__((ext_vector_type(8))) __bf16 bf16x8;
typedef __attribute__((ext_vector_type(4))) float f32x4;

__device__ inline void gload_lds16(const void* g, void* l) {
  __builtin_amdgcn_global_load_lds(
      (const __attribute__((address_space(1))) unsigned int*)g,
      (__attribute__((address_space(3))) unsigned int*)l, 16, 0, 0);
}

// ---------------- weight f32 -> bf16, LDS-image layout (r7-proven) ----------------
__global__ __launch_bounds__(256) void wconv_kernel(const float* __restrict__ wq,
                                                    const float* __restrict__ wk,
                                                    const float* __restrict__ wv,
                                                    bf16* __restrict__ wb) {
  int c = blockIdx.x * 256 + threadIdx.x;   // 98304 chunks of 8 bf16
  int l   = c & 63;
  int n   = (c >> 6) & 3;
  int kc2 = (c >> 8) & 1;
  int ks  = (c >> 9) & 15;
  int p   = c >> 13;
  const float* src = (p == 0) ? wq : ((p == 1) ? wk : wv);
  int row = n * 16 + (l & 15);
  int k8  = ks * 64 + kc2 * 32 + (l >> 4) * 8;
  const float4* ap = reinterpret_cast<const float4*>(src + (size_t)row * DIN + k8);
  float4 a0 = ap[0], a1 = ap[1];
  bf16x8 av;
  av[0]=(bf16)a0.x; av[1]=(bf16)a0.y; av[2]=(bf16)a0.z; av[3]=(bf16)a0.w;
  av[4]=(bf16)a1.x; av[5]=(bf16)a1.y; av[6]=(bf16)a1.z; av[7]=(bf16)a1.w;
  *reinterpret_cast<bf16x8*>(wb + (size_t)c * 8) = av;
}

// ---------------- QKV projection r14: triple-buffered gload_lds, depth-2 prefetch ----
// grid (256,3), block 256 (4 waves). BM=64, BN=64, BK=64. 72 KB LDS -> 2 blk/CU.
// Same staging/read/store as r10/r13 (proven); the waited-on stage is now issued
// TWO iterations ahead (vmcnt(12) leaves 2 stages in flight) -> latency slack x2.
__global__ __launch_bounds__(256) void proj_kernel(
    const float* __restrict__ inq, const float* __restrict__ ink, const float* __restrict__ inv,
    const bf16* __restrict__ wb_all,
    bf16* __restrict__ qb, bf16* __restrict__ kb, bf16* __restrict__ vt) {
  const int p = blockIdx.y;
  const float* in = (p == 0) ? inq : ((p == 1) ? ink : inv);
  const bf16* wbp = wb_all + (size_t)p * 16 * 4096;   // 16 ks-blocks of 4096 bf16
  const int tid  = threadIdx.x;
  const int lane = tid & 63;
  const int w    = tid >> 6;
  const int col16 = lane & 15, g = lane >> 4;
  const int row0 = blockIdx.x * 64;

  __shared__ float As[3][4096];   // 3 x 16 KB
  __shared__ bf16  Bs[3][4096];   // 3 x  8 KB

  const int arow_l = w * 16 + (lane >> 4);           // + j*4
  const int aswz0  = (lane & 15) * 16;               // within-row byte, pre-XOR
  #define STAGE(buf, ks)                                                          \
    {                                                                             \
      _Pragma("unroll")                                                           \
      for (int j = 0; j < 4; j++) {                                               \
        int row = arow_l + j * 4;                                                 \
        int swb = aswz0 ^ ((row & 7) << 5);                                       \
        const char* gp = (const char*)(in + (size_t)(row0 + row) * DIN + (ks) * 64) + swb; \
        gload_lds16(gp, (char*)&As[buf][0] + w * 4096 + j * 1024);                \
      }                                                                           \
      _Pragma("unroll")                                                           \
      for (int j = 0; j < 2; j++) {                                               \
        const char* gp = (const char*)(wbp + (size_t)(ks) * 4096) + w * 2048 + j * 1024 + lane * 16; \
        gload_lds16(gp, (char*)&Bs[buf][0] + w * 2048 + j * 1024);                \
      }                                                                           \
    }

  f32x4 acc[4] = {};

  STAGE(0, 0);
  STAGE(1, 1);

  for (int ks = 0; ks < 16; ks++) {
    const int buf = ks % 3;
    if (ks < 14) {
      STAGE((ks + 2) % 3, ks + 2);
      // stage(ks) complete; stage(ks+1), stage(ks+2) = 12 ops stay in flight
      asm volatile("s_waitcnt vmcnt(12)" ::: "memory");
    } else if (ks == 14) {
      asm volatile("s_waitcnt vmcnt(6)" ::: "memory");
    } else {
      asm volatile("s_waitcnt vmcnt(0)" ::: "memory");
    }
    __builtin_amdgcn_s_barrier();

    const char* ab = (const char*)&As[buf][0] + w * 4096 + col16 * 256;
    const char* bb = (const char*)&Bs[buf][0] + lane * 16;
    #pragma unroll
    for (int kc = 0; kc < 2; kc++) {
      int abyte = (kc * 128 + g * 32) ^ ((col16 & 7) << 5);
      f32x4 a0 = *reinterpret_cast<const f32x4*>(ab + abyte);
      f32x4 a1 = *reinterpret_cast<const f32x4*>(ab + abyte + 16);
      bf16x8 av;
      av[0]=(bf16)a0[0]; av[1]=(bf16)a0[1]; av[2]=(bf16)a0[2]; av[3]=(bf16)a0[3];
      av[4]=(bf16)a1[0]; av[5]=(bf16)a1[1]; av[6]=(bf16)a1[2]; av[7]=(bf16)a1[3];
      #pragma unroll
      for (int n = 0; n < 4; n++) {
        bf16x8 bv = *reinterpret_cast<const bf16x8*>(bb + kc * 4096 + n * 1024);
        acc[n] = __builtin_amdgcn_mfma_f32_16x16x32_bf16(av, bv, acc[n], 0, 0, 0);
      }
    }
    asm volatile("s_waitcnt lgkmcnt(0)" ::: "memory");  // my reads of buf done
    __builtin_amdgcn_s_barrier();                       // all waves done with buf
  }
  #undef STAGE

  const int rowbase = row0 + w * 16 + g * 4;
  #pragma unroll
  for (int n = 0; n < 4; n++)
    #pragma unroll
    for (int rg = 0; rg < 4; rg++) {
      int rr = rowbase + rg;
      int cc = n * 16 + col16;
      if (p == 0)      qb[(size_t)rr * DH + cc] = (bf16)acc[n][rg];
      else if (p == 1) kb[(size_t)rr * DH + cc] = (bf16)acc[n][rg];
      else {
        int bb2 = rr >> 11, ss = rr & 2047;
        vt[((size_t)bb2 * DH + cc) * S_ + ss] = (bf16)acc[n][rg];
      }
    }
}

// ---------------- causal flash attention, KV-split across 8 waves ----------------
// grid: (S/16, B), block = 512 threads (8 waves).  (r13, proven)
__global__ __launch_bounds__(512) void attn_kernel(
    const bf16* __restrict__ qb, const bf16* __restrict__ kb, const bf16* __restrict__ vt,
    float* __restrict__ out) {
  const int qt = blockIdx.x;
  const int b  = blockIdx.y;
  const int lane = threadIdx.x & 63;
  const int w    = threadIdx.x >> 6;       // wave 0..7
  const int col16 = lane & 15, g = lane >> 4;
  const int row0 = qt * 16;                // q rows row0..row0+15

  __shared__ float pacc[8][16][68];        // padded leading dim
  __shared__ float pm[8][16];
  __shared__ float pl_[8][16];
  __shared__ bf16 plds[8][16 * 64];
  bf16* pl = plds[w];

  bf16x8 qf[2];
  {
    const bf16* qrow = qb + ((size_t)(b * S_ + row0 + col16)) * DH + g * 8;
    qf[0] = *reinterpret_cast<const bf16x8*>(qrow);
    qf[1] = *reinterpret_cast<const bf16x8*>(qrow + 32);
  }

  f32x4 acc[4] = {};
  float m_r[4], l_r[4];
  #pragma unroll
  for (int i = 0; i < 4; i++) { m_r[i] = -1e30f; l_r[i] = 0.f; }

  const int nt = (qt + 4) >> 2;            // causal kv-tile count (KVBLK=64)

  for (int t = w; t < nt; t += 8) {
    const int kvb = t * 64;
    f32x4 s[4] = {};
    #pragma unroll
    for (int n = 0; n < 4; n++) {
      const bf16* krow = kb + ((size_t)(b * S_ + kvb + n*16 + col16)) * DH + g * 8;
      bf16x8 kf0 = *reinterpret_cast<const bf16x8*>(krow);
      bf16x8 kf1 = *reinterpret_cast<const bf16x8*>(krow + 32);
      s[n] = __builtin_amdgcn_mfma_f32_16x16x32_bf16(qf[0], kf0, s[n], 0, 0, 0);
      s[n] = __builtin_amdgcn_mfma_f32_16x16x32_bf16(qf[1], kf1, s[n], 0, 0, 0);
    }
    float vals[4][4];
    const bool diag = (t == nt - 1);
    #pragma unroll
    for (int n = 0; n < 4; n++)
      #pragma unroll
      for (int rg = 0; rg < 4; rg++) {
        float v = s[n][rg] * 0.125f;
        if (diag) {
          int kvp = kvb + n*16 + col16;
          int qp  = row0 + g*4 + rg;
          if (kvp > qp) v = -1e30f;
        }
        vals[n][rg] = v;
      }
    float rmax[4];
    #pragma unroll
    for (int rg = 0; rg < 4; rg++)
      rmax[rg] = fmaxf(fmaxf(vals[0][rg], vals[1][rg]), fmaxf(vals[2][rg], vals[3][rg]));
    #pragma unroll
    for (int off = 1; off < 16; off <<= 1)
      #pragma unroll
      for (int rg = 0; rg < 4; rg++)
        rmax[rg] = fmaxf(rmax[rg], __shfl_xor(rmax[rg], off));
    float scl[4], rsum[4];
    #pragma unroll
    for (int rg = 0; rg < 4; rg++) {
      float mn = fmaxf(m_r[rg], rmax[rg]);
      scl[rg] = __expf(m_r[rg] - mn);
      m_r[rg] = mn;
      rsum[rg] = 0.f;
    }
    #pragma unroll
    for (int n = 0; n < 4; n++)
      #pragma unroll
      for (int rg = 0; rg < 4; rg++) {
        float pp = __expf(vals[n][rg] - m_r[rg]);
        vals[n][rg] = pp;
        rsum[rg] += pp;
      }
    #pragma unroll
    for (int off = 1; off < 16; off <<= 1)
      #pragma unroll
      for (int rg = 0; rg < 4; rg++)
        rsum[rg] += __shfl_xor(rsum[rg], off);
    #pragma unroll
    for (int rg = 0; rg < 4; rg++)
      l_r[rg] = l_r[rg] * scl[rg] + rsum[rg];
    #pragma unroll
    for (int n = 0; n < 4; n++)
      #pragma unroll
      for (int rg = 0; rg < 4; rg++)
        acc[n][rg] *= scl[rg];
    #pragma unroll
    for (int n = 0; n < 4; n++)
      #pragma unroll
      for (int rg = 0; rg < 4; rg++) {
        int row = g*4 + rg;
        int idx = (row * 64 + n*16 + col16) ^ ((row & 7) << 3);
        pl[idx] = (bf16)vals[n][rg];
      }
    bf16x8 pa[2];
    {
      int row = col16;
      int i0 = (row * 64 + 0  + g * 8) ^ ((row & 7) << 3);
      int i1 = (row * 64 + 32 + g * 8) ^ ((row & 7) << 3);
      pa[0] = *reinterpret_cast<const bf16x8*>(&pl[i0]);
      pa[1] = *reinterpret_cast<const bf16x8*>(&pl[i1]);
    }
    #pragma unroll
    for (int nd = 0; nd < 4; nd++) {
      const bf16* vrow = vt + ((size_t)(b * DH + nd*16 + col16)) * S_ + kvb + g * 8;
      bf16x8 v0 = *reinterpret_cast<const bf16x8*>(vrow);
      bf16x8 v1 = *reinterpret_cast<const bf16x8*>(vrow + 32);
      acc[nd] = __builtin_amdgcn_mfma_f32_16x16x32_bf16(pa[0], v0, acc[nd], 0, 0, 0);
      acc[nd] = __builtin_amdgcn_mfma_f32_16x16x32_bf16(pa[1], v1, acc[nd], 0, 0, 0);
    }
  }

  #pragma unroll
  for (int n = 0; n < 4; n++)
    #pragma unroll
    for (int rg = 0; rg < 4; rg++)
      pacc[w][g*4 + rg][n*16 + col16] = acc[n][rg];
  if (col16 == 0) {
    #pragma unroll
    for (int rg = 0; rg < 4; rg++) {
      pm[w][g*4 + rg]  = m_r[rg];
      pl_[w][g*4 + rg] = l_r[rg];
    }
  }
  __syncthreads();

  const int tid = threadIdx.x;
  #pragma unroll
  for (int i = 0; i < 2; i++) {
    int idx = tid + i * 512;
    int row = idx >> 6, col = idx & 63;
    float M = -1e30f;
    #pragma unroll
    for (int ww = 0; ww < 8; ww++) M = fmaxf(M, pm[ww][row]);
    float L = 0.f, o = 0.f;
    #pragma unroll
    for (int ww = 0; ww < 8; ww++) {
      float e = __expf(pm[ww][row] - M);
      L += pl_[ww][row] * e;
      o += pacc[ww][row][col] * e;
    }
    out[((size_t)b * S_ + row0 + row) * DH + col] = o / L;
  }
}

extern "C" void kernel_launch(void* const* d_in, const int* in_sizes, int n_in,
                              void* d_out, int out_size, void* d_ws, size_t ws_size,
                              hipStream_t stream) {
  const float* q  = (const float*)d_in[0];
  const float* k  = (const float*)d_in[1];
  const float* v  = (const float*)d_in[2];
  const float* wq = (const float*)d_in[3];
  const float* wk = (const float*)d_in[4];
  const float* wv = (const float*)d_in[5];

  char* ws = (char*)d_ws;
  bf16* Wb = (bf16*)(ws);                         // 1.5 MB LDS-image weights
  bf16* Qb = (bf16*)(ws + 1572864);               // 2 MB
  bf16* Kb = (bf16*)(ws + 3670016);               // 2 MB
  bf16* Vt = (bf16*)(ws + 5767168);               // 2 MB (transposed [B][DH][S])

  wconv_kernel<<<dim3(384), 256, 0, stream>>>(wq, wk, wv, Wb);
  proj_kernel<<<dim3(B_ * S_ / 64, 3), 256, 0, stream>>>(q, k, v, Wb, Qb, Kb, Vt);
  attn_kernel<<<dim3(S_ / 16, B_), 512, 0, stream>>>(Qb, Kb, Vt, (float*)d_out);
}

// Round 15
// 93.052 us; speedup vs baseline: 1.0450x; 1.0450x over previous
//
#include <hip/hip_runtime.h>
#include <hip/hip_bf16.h>

#define B_  8
#define S_  2048
#define DIN 1024
#define DH  64

typedef __bf16 bf16;
typedef __attribute__((ext_vector_type(8))) __bf16 bf16x8;
typedef __attribute__((ext_vector_type(4))) float f32x4;

__device__ inline void gload_lds16(const void* g, void* l) {
  __builtin_amdgcn_global_load_lds(
      (const __attribute__((address_space(1))) unsigned int*)g,
      (__attribute__((address_space(3))) unsigned int*)l, 16, 0, 0);
}

// ---------------- weight f32 -> bf16, LDS-image layout (r7-proven) ----------------
// Wb[p][ks] is a linear 8KB block equal to the B-LDS image:
// value = W_p[n*16 + lane%16][ks*64 + kc2*32 + (lane/16)*8 + i]
__global__ __launch_bounds__(256) void wconv_kernel(const float* __restrict__ wq,
                                                    const float* __restrict__ wk,
                                                    const float* __restrict__ wv,
                                                    bf16* __restrict__ wb) {
  int c = blockIdx.x * 256 + threadIdx.x;   // 98304 chunks of 8 bf16
  int l   = c & 63;
  int n   = (c >> 6) & 3;
  int kc2 = (c >> 8) & 1;
  int ks  = (c >> 9) & 15;
  int p   = c >> 13;
  const float* src = (p == 0) ? wq : ((p == 1) ? wk : wv);
  int row = n * 16 + (l & 15);
  int k8  = ks * 64 + kc2 * 32 + (l >> 4) * 8;
  const float4* ap = reinterpret_cast<const float4*>(src + (size_t)row * DIN + k8);
  float4 a0 = ap[0], a1 = ap[1];
  bf16x8 av;
  av[0]=(bf16)a0.x; av[1]=(bf16)a0.y; av[2]=(bf16)a0.z; av[3]=(bf16)a0.w;
  av[4]=(bf16)a1.x; av[5]=(bf16)a1.y; av[6]=(bf16)a1.z; av[7]=(bf16)a1.w;
  *reinterpret_cast<bf16x8*>(wb + (size_t)c * 8) = av;
}

// ---------------- QKV projection (r13 best): gload_lds dbuf + counted vmcnt ----
// grid (256,3), block 256 (4 waves). BM=64, BN=64, BK=64. 48 KB LDS -> 3 blk/CU.
__global__ __launch_bounds__(256) void proj_kernel(
    const float* __restrict__ inq, const float* __restrict__ ink, const float* __restrict__ inv,
    const bf16* __restrict__ wb_all,
    bf16* __restrict__ qb, bf16* __restrict__ kb, bf16* __restrict__ vt) {
  const int p = blockIdx.y;
  const float* in = (p == 0) ? inq : ((p == 1) ? ink : inv);
  const bf16* wbp = wb_all + (size_t)p * 16 * 4096;   // 16 ks-blocks of 4096 bf16
  const int tid  = threadIdx.x;
  const int lane = tid & 63;
  const int w    = tid >> 6;
  const int col16 = lane & 15, g = lane >> 4;
  const int row0 = blockIdx.x * 64;

  __shared__ float As[2][4096];   // 2 x 16 KB
  __shared__ bf16  Bs[2][4096];   // 2 x  8 KB

  const int arow_l = w * 16 + (lane >> 4);           // + j*4
  const int aswz0  = (lane & 15) * 16;               // within-row byte, pre-XOR
  #define STAGE(buf, ks)                                                          \
    {                                                                             \
      _Pragma("unroll")                                                           \
      for (int j = 0; j < 4; j++) {                                               \
        int row = arow_l + j * 4;                                                 \
        int swb = aswz0 ^ ((row & 7) << 5);                                       \
        const char* gp = (const char*)(in + (size_t)(row0 + row) * DIN + (ks) * 64) + swb; \
        gload_lds16(gp, (char*)&As[buf][0] + w * 4096 + j * 1024);                \
      }                                                                           \
      _Pragma("unroll")                                                           \
      for (int j = 0; j < 2; j++) {                                               \
        const char* gp = (const char*)(wbp + (size_t)(ks) * 4096) + w * 2048 + j * 1024 + lane * 16; \
        gload_lds16(gp, (char*)&Bs[buf][0] + w * 2048 + j * 1024);                \
      }                                                                           \
    }

  f32x4 acc[4] = {};

  STAGE(0, 0);

  for (int ks = 0; ks < 16; ks++) {
    const int buf = ks & 1;
    if (ks < 15) {
      STAGE(buf ^ 1, ks + 1);
      asm volatile("s_waitcnt vmcnt(6)" ::: "memory");  // stage(ks) done; next stays in flight
    } else {
      asm volatile("s_waitcnt vmcnt(0)" ::: "memory");
    }
    __builtin_amdgcn_s_barrier();

    const char* ab = (const char*)&As[buf][0] + w * 4096 + col16 * 256;
    const char* bb = (const char*)&Bs[buf][0] + lane * 16;
    #pragma unroll
    for (int kc = 0; kc < 2; kc++) {
      int abyte = (kc * 128 + g * 32) ^ ((col16 & 7) << 5);
      f32x4 a0 = *reinterpret_cast<const f32x4*>(ab + abyte);
      f32x4 a1 = *reinterpret_cast<const f32x4*>(ab + abyte + 16);
      bf16x8 av;
      av[0]=(bf16)a0[0]; av[1]=(bf16)a0[1]; av[2]=(bf16)a0[2]; av[3]=(bf16)a0[3];
      av[4]=(bf16)a1[0]; av[5]=(bf16)a1[1]; av[6]=(bf16)a1[2]; av[7]=(bf16)a1[3];
      #pragma unroll
      for (int n = 0; n < 4; n++) {
        bf16x8 bv = *reinterpret_cast<const bf16x8*>(bb + kc * 4096 + n * 1024);
        acc[n] = __builtin_amdgcn_mfma_f32_16x16x32_bf16(av, bv, acc[n], 0, 0, 0);
      }
    }
    asm volatile("s_waitcnt lgkmcnt(0)" ::: "memory");
    __builtin_amdgcn_s_barrier();
  }
  #undef STAGE

  const int rowbase = row0 + w * 16 + g * 4;
  #pragma unroll
  for (int n = 0; n < 4; n++)
    #pragma unroll
    for (int rg = 0; rg < 4; rg++) {
      int rr = rowbase + rg;
      int cc = n * 16 + col16;
      if (p == 0)      qb[(size_t)rr * DH + cc] = (bf16)acc[n][rg];
      else if (p == 1) kb[(size_t)rr * DH + cc] = (bf16)acc[n][rg];
      else {
        int bb2 = rr >> 11, ss = rr & 2047;
        vt[((size_t)bb2 * DH + cc) * S_ + ss] = (bf16)acc[n][rg];
      }
    }
}

// ---------------- causal flash attention, KV-split across 8 waves ----------------
// grid: (S/16, B), block = 512 threads (8 waves). pacc padded 64->68 to break
// the 4-way bank conflict on partial stores (2-way after padding = free, m136).
__global__ __launch_bounds__(512) void attn_kernel(
    const bf16* __restrict__ qb, const bf16* __restrict__ kb, const bf16* __restrict__ vt,
    float* __restrict__ out) {
  const int qt = blockIdx.x;
  const int b  = blockIdx.y;
  const int lane = threadIdx.x & 63;
  const int w    = threadIdx.x >> 6;       // wave 0..7
  const int col16 = lane & 15, g = lane >> 4;
  const int row0 = qt * 16;                // q rows row0..row0+15

  __shared__ float pacc[8][16][68];        // padded leading dim
  __shared__ float pm[8][16];
  __shared__ float pl_[8][16];
  __shared__ bf16 plds[8][16 * 64];
  bf16* pl = plds[w];

  bf16x8 qf[2];
  {
    const bf16* qrow = qb + ((size_t)(b * S_ + row0 + col16)) * DH + g * 8;
    qf[0] = *reinterpret_cast<const bf16x8*>(qrow);
    qf[1] = *reinterpret_cast<const bf16x8*>(qrow + 32);
  }

  f32x4 acc[4] = {};
  float m_r[4], l_r[4];
  #pragma unroll
  for (int i = 0; i < 4; i++) { m_r[i] = -1e30f; l_r[i] = 0.f; }

  const int nt = (qt + 4) >> 2;            // causal kv-tile count (KVBLK=64)

  for (int t = w; t < nt; t += 8) {
    const int kvb = t * 64;
    f32x4 s[4] = {};
    #pragma unroll
    for (int n = 0; n < 4; n++) {
      const bf16* krow = kb + ((size_t)(b * S_ + kvb + n*16 + col16)) * DH + g * 8;
      bf16x8 kf0 = *reinterpret_cast<const bf16x8*>(krow);
      bf16x8 kf1 = *reinterpret_cast<const bf16x8*>(krow + 32);
      s[n] = __builtin_amdgcn_mfma_f32_16x16x32_bf16(qf[0], kf0, s[n], 0, 0, 0);
      s[n] = __builtin_amdgcn_mfma_f32_16x16x32_bf16(qf[1], kf1, s[n], 0, 0, 0);
    }
    float vals[4][4];
    const bool diag = (t == nt - 1);
    #pragma unroll
    for (int n = 0; n < 4; n++)
      #pragma unroll
      for (int rg = 0; rg < 4; rg++) {
        float v = s[n][rg] * 0.125f;
        if (diag) {
          int kvp = kvb + n*16 + col16;
          int qp  = row0 + g*4 + rg;
          if (kvp > qp) v = -1e30f;
        }
        vals[n][rg] = v;
      }
    float rmax[4];
    #pragma unroll
    for (int rg = 0; rg < 4; rg++)
      rmax[rg] = fmaxf(fmaxf(vals[0][rg], vals[1][rg]), fmaxf(vals[2][rg], vals[3][rg]));
    #pragma unroll
    for (int off = 1; off < 16; off <<= 1)
      #pragma unroll
      for (int rg = 0; rg < 4; rg++)
        rmax[rg] = fmaxf(rmax[rg], __shfl_xor(rmax[rg], off));
    float scl[4], rsum[4];
    #pragma unroll
    for (int rg = 0; rg < 4; rg++) {
      float mn = fmaxf(m_r[rg], rmax[rg]);
      scl[rg] = __expf(m_r[rg] - mn);
      m_r[rg] = mn;
      rsum[rg] = 0.f;
    }
    #pragma unroll
    for (int n = 0; n < 4; n++)
      #pragma unroll
      for (int rg = 0; rg < 4; rg++) {
        float pp = __expf(vals[n][rg] - m_r[rg]);
        vals[n][rg] = pp;
        rsum[rg] += pp;
      }
    #pragma unroll
    for (int off = 1; off < 16; off <<= 1)
      #pragma unroll
      for (int rg = 0; rg < 4; rg++)
        rsum[rg] += __shfl_xor(rsum[rg], off);
    #pragma unroll
    for (int rg = 0; rg < 4; rg++)
      l_r[rg] = l_r[rg] * scl[rg] + rsum[rg];
    #pragma unroll
    for (int n = 0; n < 4; n++)
      #pragma unroll
      for (int rg = 0; rg < 4; rg++)
        acc[n][rg] *= scl[rg];
    #pragma unroll
    for (int n = 0; n < 4; n++)
      #pragma unroll
      for (int rg = 0; rg < 4; rg++) {
        int row = g*4 + rg;
        int idx = (row * 64 + n*16 + col16) ^ ((row & 7) << 3);
        pl[idx] = (bf16)vals[n][rg];
      }
    bf16x8 pa[2];
    {
      int row = col16;
      int i0 = (row * 64 + 0  + g * 8) ^ ((row & 7) << 3);
      int i1 = (row * 64 + 32 + g * 8) ^ ((row & 7) << 3);
      pa[0] = *reinterpret_cast<const bf16x8*>(&pl[i0]);
      pa[1] = *reinterpret_cast<const bf16x8*>(&pl[i1]);
    }
    #pragma unroll
    for (int nd = 0; nd < 4; nd++) {
      const bf16* vrow = vt + ((size_t)(b * DH + nd*16 + col16)) * S_ + kvb + g * 8;
      bf16x8 v0 = *reinterpret_cast<const bf16x8*>(vrow);
      bf16x8 v1 = *reinterpret_cast<const bf16x8*>(vrow + 32);
      acc[nd] = __builtin_amdgcn_mfma_f32_16x16x32_bf16(pa[0], v0, acc[nd], 0, 0, 0);
      acc[nd] = __builtin_amdgcn_mfma_f32_16x16x32_bf16(pa[1], v1, acc[nd], 0, 0, 0);
    }
  }

  #pragma unroll
  for (int n = 0; n < 4; n++)
    #pragma unroll
    for (int rg = 0; rg < 4; rg++)
      pacc[w][g*4 + rg][n*16 + col16] = acc[n][rg];
  if (col16 == 0) {
    #pragma unroll
    for (int rg = 0; rg < 4; rg++) {
      pm[w][g*4 + rg]  = m_r[rg];
      pl_[w][g*4 + rg] = l_r[rg];
    }
  }
  __syncthreads();

  const int tid = threadIdx.x;
  #pragma unroll
  for (int i = 0; i < 2; i++) {
    int idx = tid + i * 512;
    int row = idx >> 6, col = idx & 63;
    float M = -1e30f;
    #pragma unroll
    for (int ww = 0; ww < 8; ww++) M = fmaxf(M, pm[ww][row]);
    float L = 0.f, o = 0.f;
    #pragma unroll
    for (int ww = 0; ww < 8; ww++) {
      float e = __expf(pm[ww][row] - M);
      L += pl_[ww][row] * e;
      o += pacc[ww][row][col] * e;
    }
    out[((size_t)b * S_ + row0 + row) * DH + col] = o / L;
  }
}

extern "C" void kernel_launch(void* const* d_in, const int* in_sizes, int n_in,
                              void* d_out, int out_size, void* d_ws, size_t ws_size,
                              hipStream_t stream) {
  const float* q  = (const float*)d_in[0];
  const float* k  = (const float*)d_in[1];
  const float* v  = (const float*)d_in[2];
  const float* wq = (const float*)d_in[3];
  const float* wk = (const float*)d_in[4];
  const float* wv = (const float*)d_in[5];

  char* ws = (char*)d_ws;
  bf16* Wb = (bf16*)(ws);                         // 1.5 MB LDS-image weights
  bf16* Qb = (bf16*)(ws + 1572864);               // 2 MB
  bf16* Kb = (bf16*)(ws + 3670016);               // 2 MB
  bf16* Vt = (bf16*)(ws + 5767168);               // 2 MB (transposed [B][DH][S])

  wconv_kernel<<<dim3(384), 256, 0, stream>>>(wq, wk, wv, Wb);
  proj_kernel<<<dim3(B_ * S_ / 64, 3), 256, 0, stream>>>(q, k, v, Wb, Qb, Kb, Vt);
  attn_kernel<<<dim3(S_ / 16, B_), 512, 0, stream>>>(Qb, Kb, Vt, (float*)d_out);
}